// Round 18
// baseline (89.127 us; speedup 1.0000x reference)
//
#include <hip/hip_runtime.h>
#include <hip/hip_fp16.h>

#define LSEQ 32768
#define HDIM 256
#define PDIM 256
#define CHUNK 64
#define NCHUNK 512   // LSEQ / CHUNK

typedef __attribute__((ext_vector_type(8))) short short8;
typedef __attribute__((ext_vector_type(8))) _Float16 half8;
typedef __attribute__((ext_vector_type(4))) float f32x4;

static __device__ __forceinline__ unsigned short f2bf(float f) {
    unsigned int u = __float_as_uint(f);
    return (unsigned short)((u + 0x7FFFu + ((u >> 16) & 1u)) >> 16);
}
// packed f32x2 -> bf16x2 in one VALU op (low word = a, high word = b)
static __device__ __forceinline__ unsigned int cvtpk_bf16(float a, float b) {
    unsigned int r;
    asm("v_cvt_pk_bf16_f32 %0, %1, %2" : "=v"(r) : "v"(a), "v"(b));
    return r;
}
// packed f32x2 -> fp16x2 (round-to-nearest); low = a, high = b
static __device__ __forceinline__ unsigned int pack_f16(float a, float b) {
    __half2 h = __floats2half2_rn(a, b);
    return *(unsigned int*)&h;
}
static __device__ __forceinline__ float2 unpack_f16(unsigned int v) {
    __half2 h = *(__half2*)&v;
    return __half22float2(h);
}
static __device__ __forceinline__ short half_bits(float x) {
    __half h = __float2half(x);
    return *(short*)&h;
}

// fragment-major weight index (VALIDATED r8/r9/r10/r12/r15):
//   frag = (k>>5)*(N/16) + (n>>4);  lane = (n&15) + (((k>>3)&3)<<4);  e = k&7
static __device__ __forceinline__ size_t fragidx(int n, int k, int ntiles) {
    return ((size_t)((k >> 5) * ntiles + (n >> 4))) * 512 +
           (size_t)(((n & 15) + (((k >> 3) & 3) << 4)) * 8 + (k & 7));
}

// ---------------------------------------------------------------------------
// prep: grid 256 x 256 thr. (r15-proven, verbatim)
// ---------------------------------------------------------------------------
__global__ void s5_prep(const float* __restrict__ Lambda,
                        const float* __restrict__ log_step,
                        const float* __restrict__ B,
                        const float* __restrict__ C,
                        float* __restrict__ Abar,
                        float* __restrict__ powt,
                        short* __restrict__ W1F,
                        short* __restrict__ W2F)
{
    const int b = blockIdx.x, t = threadIdx.x;

    {   // discretization for p = t
        float lr = Lambda[2 * t], li = Lambda[2 * t + 1];
        float step = expf(log_step[t]);
        float s2 = 0.5f * step;
        float dr = 1.0f - s2 * lr, di = -s2 * li;
        float inv = 1.0f / (dr * dr + di * di);
        float blr = dr * inv, bli = -di * inv;
        float nr = 1.0f + s2 * lr, ni = s2 * li;
        float ar = blr * nr - bli * ni;
        float ai = blr * ni + bli * nr;

        if (b <= 64) {   // powt[b][t] = (ar,ai)^b, iterative
            float pr = 1.0f, pi = 0.0f;
            for (int k = 0; k < b; ++k) {
                float tr = pr * ar - pi * ai;
                pi = pr * ai + pi * ar;
                pr = tr;
            }
            powt[(size_t)b * 512 + 2 * t] = pr;
            powt[(size_t)b * 512 + 2 * t + 1] = pi;
        }
        if (b == 1) { Abar[2 * t] = ar; Abar[2 * t + 1] = ai; }
    }
    {   // W1F rows for p = b (fragment-major bf16, N=512 -> ntiles=32)
        float lr = Lambda[2 * b], li = Lambda[2 * b + 1];
        float step = expf(log_step[b]);
        float s2 = 0.5f * step;
        float dr = 1.0f - s2 * lr, di = -s2 * li;
        float inv = 1.0f / (dr * dr + di * di);
        float gr = dr * inv * step, gi = -di * inv * step;
        float br = B[(size_t)(b * HDIM + t) * 2];
        float bi = B[(size_t)(b * HDIM + t) * 2 + 1];
        W1F[fragidx(2 * b,     t, 32)] = (short)f2bf(gr * br - gi * bi);
        W1F[fragidx(2 * b + 1, t, 32)] = (short)f2bf(gr * bi + gi * br);
    }
    {   // W2F row h = b (fragment-major FP16, N=256 -> ntiles=16, K=512)
        float cr = C[(size_t)(b * PDIM + t) * 2];
        float ci = C[(size_t)(b * PDIM + t) * 2 + 1];
        W2F[fragidx(b, 2 * t,     16)] = half_bits(cr);
        W2F[fragidx(b, 2 * t + 1, 16)] = half_bits(-ci);
    }
}

// ---------------------------------------------------------------------------
// k1: r15-proven, verbatim. ONE block per chunk, 512 thr / 8 waves.
// Barrier-free GEMM1 (bf16, W1F direct); 2-segment scan; xs fp16.
// ---------------------------------------------------------------------------
__global__ __launch_bounds__(512, 4) void s5_k1(const float* __restrict__ U,
                                                const short* __restrict__ W1F,
                                                const float* __restrict__ Abar,
                                                unsigned int* __restrict__ xs,
                                                float* __restrict__ local_end)
{
    __shared__ char smem[67584];
    short* As = (short*)smem;             // [64][264] bf16 (pad +8), 33792 B
    float* sb = (float*)smem;             // [64][260] f32 aliased after GEMM (66560 B)
    float2* sEndv = (float2*)(smem + 66560);  // [128]

    const int tid = threadIdx.x;
    const int lane = tid & 63, w = tid >> 6;
    const int wm = w >> 2, wn = w & 3;
    const int c  = blockIdx.x;
    const int m0 = c * CHUNK;

    // stage u tile -> bf16 (once per chunk)
    #pragma unroll
    for (int i = 0; i < 4; ++i) {
        int gidx = tid + i * 512;
        int row = gidx >> 5, kc = (gidx & 31) << 3;
        const float4* up = (const float4*)&U[(size_t)(m0 + row) * 256 + kc];
        float4 v0 = up[0], v1 = up[1];
        uint4 wv;
        wv.x = cvtpk_bf16(v0.x, v0.y);
        wv.y = cvtpk_bf16(v0.z, v0.w);
        wv.z = cvtpk_bf16(v1.x, v1.y);
        wv.w = cvtpk_bf16(v1.z, v1.w);
        *(uint4*)&As[row * 264 + kc] = wv;
    }
    __syncthreads();

    f32x4 acc[2][2][4] = {};   // [mi][half][ni]

    // barrier-free K-loop: A frags from LDS, B frags direct from W1F (L2)
    for (int s = 0; s < 8; ++s) {
        int k0 = s * 32;
        short8 af[2];
        #pragma unroll
        for (int mi = 0; mi < 2; ++mi)
            af[mi] = *(const short8*)&As[(wm * 32 + mi * 16 + (lane & 15)) * 264 + k0 + ((lane >> 4) << 3)];
        #pragma unroll
        for (int half = 0; half < 2; ++half) {
            short8 bfr[4];
            #pragma unroll
            for (int ni = 0; ni < 4; ++ni)
                bfr[ni] = *(const short8*)&W1F[(size_t)(s * 32 + half * 16 + wn * 4 + ni) * 512 + lane * 8];
            #pragma unroll
            for (int mi = 0; mi < 2; ++mi)
                #pragma unroll
                for (int ni = 0; ni < 4; ++ni)
                    acc[mi][half][ni] = __builtin_amdgcn_mfma_f32_16x16x32_bf16(af[mi], bfr[ni], acc[mi][half][ni], 0, 0, 0);
        }
    }
    __syncthreads();   // all As reads complete before sb overwrites it

    for (int half = 0; half < 2; ++half) {
        // acc -> scan buffer (f32, pad 260)
        #pragma unroll
        for (int mi = 0; mi < 2; ++mi) {
            int row = wm * 32 + mi * 16 + ((lane >> 4) << 2);
            #pragma unroll
            for (int ni = 0; ni < 4; ++ni) {
                int col = wn * 64 + ni * 16 + (lane & 15);
                #pragma unroll
                for (int r = 0; r < 4; ++r)
                    sb[(row + r) * 260 + col] = acc[mi][half][ni][r];
            }
        }
        __syncthreads();

        // local scan, 2-segment split: threads 0..255 active
        if (tid < 256) {
            int ch = tid & 127, seg = tid >> 7;
            int pgl = half * 128 + ch;
            float2 a = ((const float2*)Abar)[pgl];
            float xr = 0.0f, xi = 0.0f;
            if (seg == 0) {
                unsigned int* xsp = xs + (size_t)m0 * 256 + pgl;
                #pragma unroll 8
                for (int r = 0; r < 32; ++r) {
                    float2 bu = *(const float2*)&sb[r * 260 + 2 * ch];
                    float nr  = fmaf(a.x, xr, fmaf(-a.y, xi, bu.x));
                    float nim = fmaf(a.x, xi, fmaf(a.y, xr, bu.y));
                    xr = nr; xi = nim;
                    xsp[(size_t)r * 256] = pack_f16(xr, xi);
                }
                sEndv[ch] = make_float2(xr, xi);
            } else {
                #pragma unroll 8
                for (int r = 32; r < 64; ++r) {
                    float2 bu = *(const float2*)&sb[r * 260 + 2 * ch];
                    float nr  = fmaf(a.x, xr, fmaf(-a.y, xi, bu.x));
                    float nim = fmaf(a.x, xi, fmaf(a.y, xr, bu.y));
                    xr = nr; xi = nim;
                    *(float2*)&sb[r * 260 + 2 * ch] = make_float2(xr, xi);
                }
            }
        }
        __syncthreads();
        if (tid >= 128 && tid < 256) {
            int ch = tid & 127;
            int pgl = half * 128 + ch;
            float2 a = ((const float2*)Abar)[pgl];
            float2 I = sEndv[ch];
            float wr = a.x, wi = a.y;
            unsigned int* xsp = xs + (size_t)m0 * 256 + pgl;
            float xr = 0.0f, xi = 0.0f;
            #pragma unroll 8
            for (int r = 32; r < 64; ++r) {
                float2 y = *(const float2*)&sb[r * 260 + 2 * ch];
                xr = y.x + wr * I.x - wi * I.y;
                xi = y.y + wr * I.y + wi * I.x;
                xsp[(size_t)r * 256] = pack_f16(xr, xi);
                float tw = wr * a.x - wi * a.y;
                wi = wr * a.y + wi * a.x;
                wr = tw;
            }
            ((float2*)local_end)[(size_t)c * 256 + pgl] = make_float2(xr, xi);
        }
        __syncthreads();   // sb/sEndv dead before next half overwrites
    }
}

// ---------------------------------------------------------------------------
// scan2: carry scan over 512 chunks (r6/r15-proven, verbatim)
// ---------------------------------------------------------------------------
__global__ void s5_scan2(const float* __restrict__ local_end,
                         float* __restrict__ carry,
                         const float* __restrict__ powt,
                         float* __restrict__ out_state)
{
    int p = threadIdx.x;
    float2 A = ((const float2*)powt)[CHUNK * 256 + p];   // Abar^64
    float cr = 0.0f, ci = 0.0f;
    for (int cb = 0; cb < NCHUNK; cb += 16) {
        float2 e[16];
        #pragma unroll
        for (int j = 0; j < 16; ++j)
            e[j] = ((const float2*)local_end)[(size_t)(cb + j) * 256 + p];
        #pragma unroll
        for (int j = 0; j < 16; ++j) {
            ((float2*)carry)[(size_t)(cb + j) * 256 + p] = make_float2(cr, ci);
            float nr = fmaf(A.x, cr, fmaf(-A.y, ci, e[j].x));
            float ni = fmaf(A.x, ci, fmaf(A.y, cr, e[j].y));
            cr = nr; ci = ni;
        }
    }
    out_state[2 * p] = cr;
    out_state[2 * p + 1] = ci;
}

// ---------------------------------------------------------------------------
// k2: r15's k2 widened to 512 thr / 8 waves (each wave owns 2 N-tiles of 16
// instead of 4) — per-output-element arithmetic BIT-IDENTICAL to r15:
// same STAGE_A thread mapping (tid<256 guard), same fixup ops, same staged
// fp16 A values, same B fragments, same MFMA order over s=0..15.
// Occupancy: 2 blocks/CU x 8 waves = 4 waves/SIMD (was 2) to hide the
// per-step W2F L2 latency. grid 512.
// ---------------------------------------------------------------------------
__global__ __launch_bounds__(512) void s5_k2(const unsigned int* __restrict__ xs,
                                             const short* __restrict__ W2F,
                                             const float* __restrict__ carry,
                                             const float* __restrict__ powt,
                                             const float* __restrict__ Dv,
                                             const float* __restrict__ U,
                                             float* __restrict__ Out)
{
    __shared__ char smem[33280];
    short* As0 = (short*)smem;                    // [64][40] fp16, 5120 B
    short* As1 = (short*)(smem + 5120);           // [64][40]
    float* carryLds = (float*)(smem + 10240);     // 512 f32, 2048 B
    float* sb = (float*)smem;                     // [32][260] f32 epilogue (alias)

    const int tid = threadIdx.x, lane = tid & 63, w = tid >> 6;   // w: 0..7
    const int c  = blockIdx.x;
    const int m0 = c * 64;
    f32x4 acc[4][2] = {};

    // STAGE thread mapping identical to r15 (threads 0..255 stage)
    const int arow = tid >> 2;            // 0..63 for tid<256
    const int akc  = (tid & 3) << 3;

    if (tid < 256)
        ((float2*)carryLds)[tid] = ((const float2*)carry)[(size_t)c * 256 + tid];
    __syncthreads();

    #define STAGE_A(S, AS)                                                        \
    if (tid < 256) {                                                              \
        int k0_ = (S) * 32;                                                       \
        uint4 xv = *(const uint4*)&xs[(size_t)(m0 + arow) * 256 + ((k0_ + akc) >> 1)]; \
        const float4* pwp = (const float4*)&powt[(size_t)(arow + 1) * 512 + k0_ + akc]; \
        float4 p0 = pwp[0], p1 = pwp[1];                                          \
        float4 c0 = *(const float4*)&carryLds[k0_ + akc];                         \
        float4 c1 = *(const float4*)&carryLds[k0_ + akc + 4];                     \
        float2 x0 = unpack_f16(xv.x);                                             \
        float2 x1 = unpack_f16(xv.y);                                             \
        float2 x2 = unpack_f16(xv.z);                                             \
        float2 x3 = unpack_f16(xv.w);                                             \
        float r0 = x0.x, i0 = x0.y;                                               \
        float r1 = x1.x, i1 = x1.y;                                               \
        float r2 = x2.x, i2 = x2.y;                                               \
        float r3 = x3.x, i3 = x3.y;                                               \
        r0 += p0.x * c0.x - p0.y * c0.y;  i0 += p0.x * c0.y + p0.y * c0.x;        \
        r1 += p0.z * c0.z - p0.w * c0.w;  i1 += p0.z * c0.w + p0.w * c0.z;        \
        r2 += p1.x * c1.x - p1.y * c1.y;  i2 += p1.x * c1.y + p1.y * c1.x;        \
        r3 += p1.z * c1.z - p1.w * c1.w;  i3 += p1.z * c1.w + p1.w * c1.z;        \
        uint4 wv;                                                                 \
        wv.x = pack_f16(r0, i0); wv.y = pack_f16(r1, i1);                         \
        wv.z = pack_f16(r2, i2); wv.w = pack_f16(r3, i3);                         \
        *(uint4*)&(AS)[arow * 40 + akc] = wv;                                     \
    }

    #define COMPUTE(S, AS)                                                        \
    {                                                                             \
        half8 af[4], bfr[2];                                                      \
        _Pragma("unroll")                                                         \
        for (int mi = 0; mi < 4; ++mi)                                            \
            af[mi] = *(const half8*)&(AS)[(mi * 16 + (lane & 15)) * 40 + ((lane >> 4) << 3)]; \
        _Pragma("unroll")                                                         \
        for (int ni = 0; ni < 2; ++ni)                                            \
            bfr[ni] = *(const half8*)&W2F[(size_t)((S) * 16 + w * 2 + ni) * 512 + lane * 8]; \
        _Pragma("unroll")                                                         \
        for (int mi = 0; mi < 4; ++mi)                                            \
            _Pragma("unroll")                                                     \
            for (int ni = 0; ni < 2; ++ni)                                        \
                acc[mi][ni] = __builtin_amdgcn_mfma_f32_16x16x32_f16(af[mi], bfr[ni], acc[mi][ni], 0, 0, 0); \
    }

    STAGE_A(0, As0);
    __syncthreads();

    for (int s = 0; s < 16; s += 2) {
        STAGE_A(s + 1, As1);
        COMPUTE(s, As0);
        __syncthreads();
        if (s + 2 < 16) STAGE_A(s + 2, As0);
        COMPUTE(s + 1, As1);
        __syncthreads();
    }

    // ---- epilogue: LDS transpose -> float4 stores (+ D*u) ----
    #pragma unroll
    for (int pass = 0; pass < 2; ++pass) {
        #pragma unroll
        for (int mi2 = 0; mi2 < 2; ++mi2) {
            int mi = pass * 2 + mi2;
            int lr0 = mi2 * 16 + ((lane >> 4) << 2);
            #pragma unroll
            for (int ni = 0; ni < 2; ++ni) {
                int col = w * 32 + ni * 16 + (lane & 15);
                #pragma unroll
                for (int r = 0; r < 4; ++r)
                    sb[(lr0 + r) * 260 + col] = acc[mi][ni][r];
            }
        }
        __syncthreads();
        #pragma unroll
        for (int j = 0; j < 4; ++j) {
            int idx = tid + j * 512;
            int lrow = idx >> 6, c4 = (idx & 63) << 2;
            int grow = m0 + pass * 32 + lrow;
            float4 v  = *(const float4*)&sb[lrow * 260 + c4];
            float4 uv = *(const float4*)&U[(size_t)grow * 256 + c4];
            float4 dv = *(const float4*)&Dv[c4];
            float4 o;
            o.x = v.x + dv.x * uv.x;
            o.y = v.y + dv.y * uv.y;
            o.z = v.z + dv.z * uv.z;
            o.w = v.w + dv.w * uv.w;
            *(float4*)&Out[(size_t)grow * 256 + c4] = o;
        }
        __syncthreads();
    }
    #undef STAGE_A
    #undef COMPUTE
}

// ---------------------------------------------------------------------------
extern "C" void kernel_launch(void* const* d_in, const int* in_sizes, int n_in,
                              void* d_out, int out_size, void* d_ws, size_t ws_size,
                              hipStream_t stream)
{
    const float* u        = (const float*)d_in[0];
    // d_in[1] = prev_state: provably never affects outputs (A_0 never enters
    // the associative-scan products; and it's zero anyway)
    const float* Lambda   = (const float*)d_in[2];
    const float* B        = (const float*)d_in[3];
    const float* C        = (const float*)d_in[4];
    const float* D        = (const float*)d_in[5];
    const float* log_step = (const float*)d_in[6];
    float* out = (float*)d_out;

    // workspace layout
    unsigned int* xs = (unsigned int*)d_ws;               // L*256 u32 (fp16 pairs) = 32 MB
    float* powt      = (float*)(xs + (size_t)LSEQ * 256); // 65*512
    float* Abar      = powt + 65 * 512;                   // 512
    float* local_end = Abar + 512;                        // 512*512
    float* carry     = local_end + (size_t)NCHUNK * 512;  // 512*512
    short* W1F       = (short*)(carry + (size_t)NCHUNK * 512); // 512*256
    short* W2F       = W1F + 512 * 256;                   // 256*512

    s5_prep<<<256, 256, 0, stream>>>(Lambda, log_step, B, C, Abar, powt, W1F, W2F);
    s5_k1<<<NCHUNK, 512, 0, stream>>>(u, W1F, Abar, xs, local_end);
    s5_scan2<<<1, 256, 0, stream>>>(local_end, carry, powt, out + (size_t)LSEQ * HDIM);
    s5_k2<<<NCHUNK, 512, 0, stream>>>(xs, W2F, carry, powt, D, u, out);
}

// Round 20
// 64.478 us; speedup vs baseline: 1.3823x; 1.3823x over previous
//
#include <hip/hip_runtime.h>
#include <hip/hip_fp16.h>

#define LSEQ 32768
#define HDIM 256
#define PDIM 256
#define CHUNK 64
#define NCHUNK 512   // LSEQ / CHUNK
#define NSUP 16      // superblocks for the carry scan
#define SUPW 32      // chunks per superblock

typedef __attribute__((ext_vector_type(8))) short short8;
typedef __attribute__((ext_vector_type(8))) _Float16 half8;
typedef __attribute__((ext_vector_type(4))) float f32x4;

static __device__ __forceinline__ unsigned short f2bf(float f) {
    unsigned int u = __float_as_uint(f);
    return (unsigned short)((u + 0x7FFFu + ((u >> 16) & 1u)) >> 16);
}
// packed f32x2 -> bf16x2 in one VALU op (low word = a, high word = b)
static __device__ __forceinline__ unsigned int cvtpk_bf16(float a, float b) {
    unsigned int r;
    asm("v_cvt_pk_bf16_f32 %0, %1, %2" : "=v"(r) : "v"(a), "v"(b));
    return r;
}
// packed f32x2 -> fp16x2 (round-to-nearest); low = a, high = b
static __device__ __forceinline__ unsigned int pack_f16(float a, float b) {
    __half2 h = __floats2half2_rn(a, b);
    return *(unsigned int*)&h;
}
static __device__ __forceinline__ float2 unpack_f16(unsigned int v) {
    __half2 h = *(__half2*)&v;
    return __half22float2(h);
}
static __device__ __forceinline__ short half_bits(float x) {
    __half h = __float2half(x);
    return *(short*)&h;
}
static __device__ __forceinline__ float2 cmul(float2 a, float2 b) {
    return make_float2(a.x * b.x - a.y * b.y, a.x * b.y + a.y * b.x);
}

// fragment-major weight index (VALIDATED r8/r9/r10/r12/r15/r18):
//   frag = (k>>5)*(N/16) + (n>>4);  lane = (n&15) + (((k>>3)&3)<<4);  e = k&7
static __device__ __forceinline__ size_t fragidx(int n, int k, int ntiles) {
    return ((size_t)((k >> 5) * ntiles + (n >> 4))) * 512 +
           (size_t)(((n & 15) + (((k >> 3) & 3) << 4)) * 8 + (k & 7));
}

// ---------------------------------------------------------------------------
// prep: grid 256 x 256 thr. (r18-proven, verbatim)
// ---------------------------------------------------------------------------
__global__ void s5_prep(const float* __restrict__ Lambda,
                        const float* __restrict__ log_step,
                        const float* __restrict__ B,
                        const float* __restrict__ C,
                        float* __restrict__ Abar,
                        float* __restrict__ powt,
                        short* __restrict__ W1F,
                        short* __restrict__ W2F)
{
    const int b = blockIdx.x, t = threadIdx.x;

    {   // discretization for p = t
        float lr = Lambda[2 * t], li = Lambda[2 * t + 1];
        float step = expf(log_step[t]);
        float s2 = 0.5f * step;
        float dr = 1.0f - s2 * lr, di = -s2 * li;
        float inv = 1.0f / (dr * dr + di * di);
        float blr = dr * inv, bli = -di * inv;
        float nr = 1.0f + s2 * lr, ni = s2 * li;
        float ar = blr * nr - bli * ni;
        float ai = blr * ni + bli * nr;

        if (b <= 64) {   // powt[b][t] = (ar,ai)^b, iterative
            float pr = 1.0f, pi = 0.0f;
            for (int k = 0; k < b; ++k) {
                float tr = pr * ar - pi * ai;
                pi = pr * ai + pi * ar;
                pr = tr;
            }
            powt[(size_t)b * 512 + 2 * t] = pr;
            powt[(size_t)b * 512 + 2 * t + 1] = pi;
        }
        if (b == 1) { Abar[2 * t] = ar; Abar[2 * t + 1] = ai; }
    }
    {   // W1F rows for p = b (fragment-major bf16, N=512 -> ntiles=32)
        float lr = Lambda[2 * b], li = Lambda[2 * b + 1];
        float step = expf(log_step[b]);
        float s2 = 0.5f * step;
        float dr = 1.0f - s2 * lr, di = -s2 * li;
        float inv = 1.0f / (dr * dr + di * di);
        float gr = dr * inv * step, gi = -di * inv * step;
        float br = B[(size_t)(b * HDIM + t) * 2];
        float bi = B[(size_t)(b * HDIM + t) * 2 + 1];
        W1F[fragidx(2 * b,     t, 32)] = (short)f2bf(gr * br - gi * bi);
        W1F[fragidx(2 * b + 1, t, 32)] = (short)f2bf(gr * bi + gi * br);
    }
    {   // W2F row h = b (fragment-major FP16, N=256 -> ntiles=16, K=512)
        float cr = C[(size_t)(b * PDIM + t) * 2];
        float ci = C[(size_t)(b * PDIM + t) * 2 + 1];
        W2F[fragidx(b, 2 * t,     16)] = half_bits(cr);
        W2F[fragidx(b, 2 * t + 1, 16)] = half_bits(-ci);
    }
}

// ---------------------------------------------------------------------------
// k1: r18-proven, verbatim. ONE block per chunk, 512 thr / 8 waves.
// ---------------------------------------------------------------------------
__global__ __launch_bounds__(512, 4) void s5_k1(const float* __restrict__ U,
                                                const short* __restrict__ W1F,
                                                const float* __restrict__ Abar,
                                                unsigned int* __restrict__ xs,
                                                float* __restrict__ local_end)
{
    __shared__ char smem[67584];
    short* As = (short*)smem;             // [64][264] bf16 (pad +8), 33792 B
    float* sb = (float*)smem;             // [64][260] f32 aliased after GEMM (66560 B)
    float2* sEndv = (float2*)(smem + 66560);  // [128]

    const int tid = threadIdx.x;
    const int lane = tid & 63, w = tid >> 6;
    const int wm = w >> 2, wn = w & 3;
    const int c  = blockIdx.x;
    const int m0 = c * CHUNK;

    // stage u tile -> bf16 (once per chunk)
    #pragma unroll
    for (int i = 0; i < 4; ++i) {
        int gidx = tid + i * 512;
        int row = gidx >> 5, kc = (gidx & 31) << 3;
        const float4* up = (const float4*)&U[(size_t)(m0 + row) * 256 + kc];
        float4 v0 = up[0], v1 = up[1];
        uint4 wv;
        wv.x = cvtpk_bf16(v0.x, v0.y);
        wv.y = cvtpk_bf16(v0.z, v0.w);
        wv.z = cvtpk_bf16(v1.x, v1.y);
        wv.w = cvtpk_bf16(v1.z, v1.w);
        *(uint4*)&As[row * 264 + kc] = wv;
    }
    __syncthreads();

    f32x4 acc[2][2][4] = {};   // [mi][half][ni]

    // barrier-free K-loop: A frags from LDS, B frags direct from W1F (L2)
    for (int s = 0; s < 8; ++s) {
        int k0 = s * 32;
        short8 af[2];
        #pragma unroll
        for (int mi = 0; mi < 2; ++mi)
            af[mi] = *(const short8*)&As[(wm * 32 + mi * 16 + (lane & 15)) * 264 + k0 + ((lane >> 4) << 3)];
        #pragma unroll
        for (int half = 0; half < 2; ++half) {
            short8 bfr[4];
            #pragma unroll
            for (int ni = 0; ni < 4; ++ni)
                bfr[ni] = *(const short8*)&W1F[(size_t)(s * 32 + half * 16 + wn * 4 + ni) * 512 + lane * 8];
            #pragma unroll
            for (int mi = 0; mi < 2; ++mi)
                #pragma unroll
                for (int ni = 0; ni < 4; ++ni)
                    acc[mi][half][ni] = __builtin_amdgcn_mfma_f32_16x16x32_bf16(af[mi], bfr[ni], acc[mi][half][ni], 0, 0, 0);
        }
    }
    __syncthreads();   // all As reads complete before sb overwrites it

    for (int half = 0; half < 2; ++half) {
        // acc -> scan buffer (f32, pad 260)
        #pragma unroll
        for (int mi = 0; mi < 2; ++mi) {
            int row = wm * 32 + mi * 16 + ((lane >> 4) << 2);
            #pragma unroll
            for (int ni = 0; ni < 4; ++ni) {
                int col = wn * 64 + ni * 16 + (lane & 15);
                #pragma unroll
                for (int r = 0; r < 4; ++r)
                    sb[(row + r) * 260 + col] = acc[mi][half][ni][r];
            }
        }
        __syncthreads();

        // local scan, 2-segment split: threads 0..255 active
        if (tid < 256) {
            int ch = tid & 127, seg = tid >> 7;
            int pgl = half * 128 + ch;
            float2 a = ((const float2*)Abar)[pgl];
            float xr = 0.0f, xi = 0.0f;
            if (seg == 0) {
                unsigned int* xsp = xs + (size_t)m0 * 256 + pgl;
                #pragma unroll 8
                for (int r = 0; r < 32; ++r) {
                    float2 bu = *(const float2*)&sb[r * 260 + 2 * ch];
                    float nr  = fmaf(a.x, xr, fmaf(-a.y, xi, bu.x));
                    float nim = fmaf(a.x, xi, fmaf(a.y, xr, bu.y));
                    xr = nr; xi = nim;
                    xsp[(size_t)r * 256] = pack_f16(xr, xi);
                }
                sEndv[ch] = make_float2(xr, xi);
            } else {
                #pragma unroll 8
                for (int r = 32; r < 64; ++r) {
                    float2 bu = *(const float2*)&sb[r * 260 + 2 * ch];
                    float nr  = fmaf(a.x, xr, fmaf(-a.y, xi, bu.x));
                    float nim = fmaf(a.x, xi, fmaf(a.y, xr, bu.y));
                    xr = nr; xi = nim;
                    *(float2*)&sb[r * 260 + 2 * ch] = make_float2(xr, xi);
                }
            }
        }
        __syncthreads();
        if (tid >= 128 && tid < 256) {
            int ch = tid & 127;
            int pgl = half * 128 + ch;
            float2 a = ((const float2*)Abar)[pgl];
            float2 I = sEndv[ch];
            float wr = a.x, wi = a.y;
            unsigned int* xsp = xs + (size_t)m0 * 256 + pgl;
            float xr = 0.0f, xi = 0.0f;
            #pragma unroll 8
            for (int r = 32; r < 64; ++r) {
                float2 y = *(const float2*)&sb[r * 260 + 2 * ch];
                xr = y.x + wr * I.x - wi * I.y;
                xi = y.y + wr * I.y + wi * I.x;
                xsp[(size_t)r * 256] = pack_f16(xr, xi);
                float tw = wr * a.x - wi * a.y;
                wi = wr * a.y + wi * a.x;
                wr = tw;
            }
            ((float2*)local_end)[(size_t)c * 256 + pgl] = make_float2(xr, xi);
        }
        __syncthreads();   // sb/sEndv dead before next half overwrites
    }
}

// ---------------------------------------------------------------------------
// scanA: 16 blocks x 256 thr. Block b: init-0 scan of its 32 chunk-ends
// (coefficient A64 = Abar^64), emit superblock end. Batched loads.
// ---------------------------------------------------------------------------
__global__ void s5_scanA(const float* __restrict__ local_end,
                         const float* __restrict__ powt,
                         float* __restrict__ scEnd)
{
    const int p = threadIdx.x, b = blockIdx.x;
    const float2 A = ((const float2*)powt)[CHUNK * 256 + p];   // Abar^64
    float cr = 0.0f, ci = 0.0f;
    for (int j0 = 0; j0 < SUPW; j0 += 16) {
        float2 e[16];
        #pragma unroll
        for (int j = 0; j < 16; ++j)
            e[j] = ((const float2*)local_end)[(size_t)(b * SUPW + j0 + j) * 256 + p];
        #pragma unroll
        for (int j = 0; j < 16; ++j) {
            float nr = fmaf(A.x, cr, fmaf(-A.y, ci, e[j].x));
            float ni = fmaf(A.x, ci, fmaf(A.y, cr, e[j].y));
            cr = nr; ci = ni;
        }
    }
    ((float2*)scEnd)[(size_t)b * 256 + p] = make_float2(cr, ci);
}

// ---------------------------------------------------------------------------
// scanB: 1 block x 256 thr. A2048 = A64^32 (5 squarings); 16-step scan of
// superblock ends -> per-superblock seeds + final state to out tail.
// ---------------------------------------------------------------------------
__global__ void s5_scanB(const float* __restrict__ scEnd,
                         const float* __restrict__ powt,
                         float* __restrict__ scSeed,
                         float* __restrict__ out_state)
{
    const int p = threadIdx.x;
    float2 AS = ((const float2*)powt)[CHUNK * 256 + p];   // Abar^64
    #pragma unroll
    for (int i = 0; i < 5; ++i) AS = cmul(AS, AS);        // Abar^2048
    float cr = 0.0f, ci = 0.0f;
    #pragma unroll
    for (int b = 0; b < NSUP; ++b) {
        ((float2*)scSeed)[(size_t)b * 256 + p] = make_float2(cr, ci);
        float2 e = ((const float2*)scEnd)[(size_t)b * 256 + p];
        float nr = fmaf(AS.x, cr, fmaf(-AS.y, ci, e.x));
        float ni = fmaf(AS.x, ci, fmaf(AS.y, cr, e.y));
        cr = nr; ci = ni;
    }
    out_state[2 * p] = cr;
    out_state[2 * p + 1] = ci;
}

// ---------------------------------------------------------------------------
// scanC: 16 blocks x 256 thr. Block b: seeded scan over its 32 chunks,
// writing per-chunk carry. Batched loads.
// ---------------------------------------------------------------------------
__global__ void s5_scanC(const float* __restrict__ local_end,
                         const float* __restrict__ powt,
                         const float* __restrict__ scSeed,
                         float* __restrict__ carry)
{
    const int p = threadIdx.x, b = blockIdx.x;
    const float2 A = ((const float2*)powt)[CHUNK * 256 + p];   // Abar^64
    float2 s = ((const float2*)scSeed)[(size_t)b * 256 + p];
    float cr = s.x, ci = s.y;
    for (int j0 = 0; j0 < SUPW; j0 += 16) {
        float2 e[16];
        #pragma unroll
        for (int j = 0; j < 16; ++j)
            e[j] = ((const float2*)local_end)[(size_t)(b * SUPW + j0 + j) * 256 + p];
        #pragma unroll
        for (int j = 0; j < 16; ++j) {
            ((float2*)carry)[(size_t)(b * SUPW + j0 + j) * 256 + p] = make_float2(cr, ci);
            float nr = fmaf(A.x, cr, fmaf(-A.y, ci, e[j].x));
            float ni = fmaf(A.x, ci, fmaf(A.y, cr, e[j].y));
            cr = nr; ci = ni;
        }
    }
}

// ---------------------------------------------------------------------------
// k2: r18-proven, verbatim. 512 thr / 8 waves, As dbuf, W2F direct fp16.
// ---------------------------------------------------------------------------
__global__ __launch_bounds__(512) void s5_k2(const unsigned int* __restrict__ xs,
                                             const short* __restrict__ W2F,
                                             const float* __restrict__ carry,
                                             const float* __restrict__ powt,
                                             const float* __restrict__ Dv,
                                             const float* __restrict__ U,
                                             float* __restrict__ Out)
{
    __shared__ char smem[33280];
    short* As0 = (short*)smem;                    // [64][40] fp16, 5120 B
    short* As1 = (short*)(smem + 5120);           // [64][40]
    float* carryLds = (float*)(smem + 10240);     // 512 f32, 2048 B
    float* sb = (float*)smem;                     // [32][260] f32 epilogue (alias)

    const int tid = threadIdx.x, lane = tid & 63, w = tid >> 6;   // w: 0..7
    const int c  = blockIdx.x;
    const int m0 = c * 64;
    f32x4 acc[4][2] = {};

    const int arow = tid >> 2;            // 0..63 for tid<256
    const int akc  = (tid & 3) << 3;

    if (tid < 256)
        ((float2*)carryLds)[tid] = ((const float2*)carry)[(size_t)c * 256 + tid];
    __syncthreads();

    #define STAGE_A(S, AS)                                                        \
    if (tid < 256) {                                                              \
        int k0_ = (S) * 32;                                                       \
        uint4 xv = *(const uint4*)&xs[(size_t)(m0 + arow) * 256 + ((k0_ + akc) >> 1)]; \
        const float4* pwp = (const float4*)&powt[(size_t)(arow + 1) * 512 + k0_ + akc]; \
        float4 p0 = pwp[0], p1 = pwp[1];                                          \
        float4 c0 = *(const float4*)&carryLds[k0_ + akc];                         \
        float4 c1 = *(const float4*)&carryLds[k0_ + akc + 4];                     \
        float2 x0 = unpack_f16(xv.x);                                             \
        float2 x1 = unpack_f16(xv.y);                                             \
        float2 x2 = unpack_f16(xv.z);                                             \
        float2 x3 = unpack_f16(xv.w);                                             \
        float r0 = x0.x, i0 = x0.y;                                               \
        float r1 = x1.x, i1 = x1.y;                                               \
        float r2 = x2.x, i2 = x2.y;                                               \
        float r3 = x3.x, i3 = x3.y;                                               \
        r0 += p0.x * c0.x - p0.y * c0.y;  i0 += p0.x * c0.y + p0.y * c0.x;        \
        r1 += p0.z * c0.z - p0.w * c0.w;  i1 += p0.z * c0.w + p0.w * c0.z;        \
        r2 += p1.x * c1.x - p1.y * c1.y;  i2 += p1.x * c1.y + p1.y * c1.x;        \
        r3 += p1.z * c1.z - p1.w * c1.w;  i3 += p1.z * c1.w + p1.w * c1.z;        \
        uint4 wv;                                                                 \
        wv.x = pack_f16(r0, i0); wv.y = pack_f16(r1, i1);                         \
        wv.z = pack_f16(r2, i2); wv.w = pack_f16(r3, i3);                         \
        *(uint4*)&(AS)[arow * 40 + akc] = wv;                                     \
    }

    #define COMPUTE(S, AS)                                                        \
    {                                                                             \
        half8 af[4], bfr[2];                                                      \
        _Pragma("unroll")                                                         \
        for (int mi = 0; mi < 4; ++mi)                                            \
            af[mi] = *(const half8*)&(AS)[(mi * 16 + (lane & 15)) * 40 + ((lane >> 4) << 3)]; \
        _Pragma("unroll")                                                         \
        for (int ni = 0; ni < 2; ++ni)                                            \
            bfr[ni] = *(const half8*)&W2F[(size_t)((S) * 16 + w * 2 + ni) * 512 + lane * 8]; \
        _Pragma("unroll")                                                         \
        for (int mi = 0; mi < 4; ++mi)                                            \
            _Pragma("unroll")                                                     \
            for (int ni = 0; ni < 2; ++ni)                                        \
                acc[mi][ni] = __builtin_amdgcn_mfma_f32_16x16x32_f16(af[mi], bfr[ni], acc[mi][ni], 0, 0, 0); \
    }

    STAGE_A(0, As0);
    __syncthreads();

    for (int s = 0; s < 16; s += 2) {
        STAGE_A(s + 1, As1);
        COMPUTE(s, As0);
        __syncthreads();
        if (s + 2 < 16) STAGE_A(s + 2, As0);
        COMPUTE(s + 1, As1);
        __syncthreads();
    }

    // ---- epilogue: LDS transpose -> float4 stores (+ D*u) ----
    #pragma unroll
    for (int pass = 0; pass < 2; ++pass) {
        #pragma unroll
        for (int mi2 = 0; mi2 < 2; ++mi2) {
            int mi = pass * 2 + mi2;
            int lr0 = mi2 * 16 + ((lane >> 4) << 2);
            #pragma unroll
            for (int ni = 0; ni < 2; ++ni) {
                int col = w * 32 + ni * 16 + (lane & 15);
                #pragma unroll
                for (int r = 0; r < 4; ++r)
                    sb[(lr0 + r) * 260 + col] = acc[mi][ni][r];
            }
        }
        __syncthreads();
        #pragma unroll
        for (int j = 0; j < 4; ++j) {
            int idx = tid + j * 512;
            int lrow = idx >> 6, c4 = (idx & 63) << 2;
            int grow = m0 + pass * 32 + lrow;
            float4 v  = *(const float4*)&sb[lrow * 260 + c4];
            float4 uv = *(const float4*)&U[(size_t)grow * 256 + c4];
            float4 dv = *(const float4*)&Dv[c4];
            float4 o;
            o.x = v.x + dv.x * uv.x;
            o.y = v.y + dv.y * uv.y;
            o.z = v.z + dv.z * uv.z;
            o.w = v.w + dv.w * uv.w;
            *(float4*)&Out[(size_t)grow * 256 + c4] = o;
        }
        __syncthreads();
    }
    #undef STAGE_A
    #undef COMPUTE
}

// ---------------------------------------------------------------------------
extern "C" void kernel_launch(void* const* d_in, const int* in_sizes, int n_in,
                              void* d_out, int out_size, void* d_ws, size_t ws_size,
                              hipStream_t stream)
{
    const float* u        = (const float*)d_in[0];
    // d_in[1] = prev_state: provably never affects outputs (A_0 never enters
    // the associative-scan products; and it's zero anyway)
    const float* Lambda   = (const float*)d_in[2];
    const float* B        = (const float*)d_in[3];
    const float* C        = (const float*)d_in[4];
    const float* D        = (const float*)d_in[5];
    const float* log_step = (const float*)d_in[6];
    float* out = (float*)d_out;

    // workspace layout
    unsigned int* xs = (unsigned int*)d_ws;               // L*256 u32 (fp16 pairs) = 32 MB
    float* powt      = (float*)(xs + (size_t)LSEQ * 256); // 65*512
    float* Abar      = powt + 65 * 512;                   // 512
    float* local_end = Abar + 512;                        // 512*512
    float* carry     = local_end + (size_t)NCHUNK * 512;  // 512*512
    float* scEnd     = carry + (size_t)NCHUNK * 512;      // 16*512
    float* scSeed    = scEnd + NSUP * 512;                // 16*512
    short* W1F       = (short*)(scSeed + NSUP * 512);     // 512*256
    short* W2F       = W1F + 512 * 256;                   // 256*512

    s5_prep<<<256, 256, 0, stream>>>(Lambda, log_step, B, C, Abar, powt, W1F, W2F);
    s5_k1<<<NCHUNK, 512, 0, stream>>>(u, W1F, Abar, xs, local_end);
    s5_scanA<<<NSUP, 256, 0, stream>>>(local_end, powt, scEnd);
    s5_scanB<<<1, 256, 0, stream>>>(scEnd, powt, scSeed, out + (size_t)LSEQ * HDIM);
    s5_scanC<<<NSUP, 256, 0, stream>>>(local_end, powt, scSeed, carry);
    s5_k2<<<NCHUNK, 512, 0, stream>>>(xs, W2F, carry, powt, D, u, out);
}